// Round 6
// baseline (323.381 us; speedup 1.0000x reference)
//
#include <hip/hip_runtime.h>
#include <hip/hip_bf16.h>

#define CCH 256
#define CQK 32
#define NHW 4096

typedef float f32x4 __attribute__((ext_vector_type(4)));
typedef _Float16 hv8 __attribute__((ext_vector_type(8)));
typedef _Float16 hv4 __attribute__((ext_vector_type(4)));

// Monotone float<->uint encoding so float max == uint max (handles negatives).
__device__ __forceinline__ unsigned enc_f32(float f) {
    unsigned u = __float_as_uint(f);
    return (u & 0x80000000u) ? ~u : (u | 0x80000000u);
}
__device__ __forceinline__ float dec_f32(unsigned u) {
    return __uint_as_float((u & 0x80000000u) ? (u ^ 0x80000000u) : ~u);
}

// ---------------------------------------------------------------------------
// Prep kernel: (a) convert Wall = concat(b_w, c_w, d_w) fp32 -> fp16 [320][256];
// (b) init m_enc = 0. Grid 144 x 256.
// ---------------------------------------------------------------------------
__global__ __launch_bounds__(256) void prep_kernel(
    const float* __restrict__ b_w, const float* __restrict__ c_w,
    const float* __restrict__ d_w, _Float16* __restrict__ Wh,
    unsigned* __restrict__ m_enc)
{
    const int bid = blockIdx.x, tid = threadIdx.x;
    if (bid < 80) {
        const int idx = (bid * 256 + tid) * 4;
        const int row = idx >> 8, col = idx & 255;
        const float* src = (row < 32) ? (b_w + row * CCH + col)
                         : (row < 64) ? (c_w + (row - 32) * CCH + col)
                                      : (d_w + (row - 64) * CCH + col);
        float4 v = *reinterpret_cast<const float4*>(src);
        _Float16* dst = Wh + (size_t)row * CCH + col;
        dst[0] = (_Float16)v.x; dst[1] = (_Float16)v.y;
        dst[2] = (_Float16)v.z; dst[3] = (_Float16)v.w;
    } else {
        m_enc[(bid - 80) * 256 + tid] = 0u;
    }
}

// ---------------------------------------------------------------------------
// Projection kernel, SWAPPED MFMA orientation: D[m=pos][n=ch] = aT^T . W^T.
// A-operand = aT rows (pos), B-operand = Wh rows (ch_out) — same loads as the
// round-5-verified kernel, operand order mirrored. C/D: row=quad*4+r -> pos,
// col=l15 -> ch. This makes dv stores 4-consecutive-pos per lane -> packed
// 8 B stores (the d-part was 40 scalar b16 stores/thread before).
// Grid: 4 batches x 128 position-tiles of 32. Block 256 = 4 waves;
// wave w owns out-channels 80w..80w+79 (5 n-frags) x 32 positions (2 m-frags).
// ---------------------------------------------------------------------------
__global__ __launch_bounds__(256) void proj_kernel(
    const float* __restrict__ a, const _Float16* __restrict__ Wh,
    const float* __restrict__ b_b, const float* __restrict__ c_b,
    const float* __restrict__ d_b,
    _Float16* __restrict__ bqT, _Float16* __restrict__ ckT,
    _Float16* __restrict__ dv)
{
    __shared__ _Float16 aT[32][CCH + 24];   // [pos][ch]; stride 560 B (16B-mult)

    const int n    = blockIdx.x >> 7;
    const int i0   = (blockIdx.x & 127) << 5;
    const int tid  = threadIdx.x;
    const int lane = tid & 63;
    const int wave = tid >> 6;
    const int l15  = lane & 15;
    const int quad = lane >> 4;

    // stage a^T tile: thread handles channel c = tid, 32 positions
    {
        const float* ap = a + (size_t)(n*CCH + tid)*NHW + i0;
        #pragma unroll
        for (int j = 0; j < 8; ++j) {
            float4 v = *reinterpret_cast<const float4*>(ap + j*4);
            aT[j*4+0][tid] = (_Float16)v.x;
            aT[j*4+1][tid] = (_Float16)v.y;
            aT[j*4+2][tid] = (_Float16)v.z;
            aT[j*4+3][tid] = (_Float16)v.w;
        }
    }
    __syncthreads();

    const f32x4 zf = {0.f, 0.f, 0.f, 0.f};
    f32x4 acc[5][2];
    #pragma unroll
    for (int t = 0; t < 5; ++t) { acc[t][0] = zf; acc[t][1] = zf; }

    const int ch0w = wave * 80;

    #pragma unroll
    for (int ks = 0; ks < 8; ++ks) {
        const int k0 = ks * 32;
        // A-frags: m = pos (l15 / l15+16), k = ch
        hv8 af0 = *reinterpret_cast<const hv8*>(&aT[l15][k0 + quad*8]);
        hv8 af1 = *reinterpret_cast<const hv8*>(&aT[16 + l15][k0 + quad*8]);
        #pragma unroll
        for (int t = 0; t < 5; ++t) {
            const int ch0 = ch0w + t*16;
            // B-frag: n = ch_out (l15), k = ch
            hv8 bf = *reinterpret_cast<const hv8*>(
                Wh + (size_t)(ch0 + l15)*CCH + k0 + quad*8);
            acc[t][0] = __builtin_amdgcn_mfma_f32_16x16x32_f16(af0, bf, acc[t][0], 0, 0, 0);
            acc[t][1] = __builtin_amdgcn_mfma_f32_16x16x32_f16(af1, bf, acc[t][1], 0, 0, 0);
        }
    }

    // epilogue: row = quad*4+r -> pos, col = l15 -> ch
    const int pos_b = i0 + quad*4;
    #pragma unroll
    for (int t = 0; t < 5; ++t) {
        const int ch0 = ch0w + t*16;
        if (ch0 < 64) {
            const float* bias_arr = (ch0 < 32) ? b_b : c_b;
            _Float16*    outp     = (ch0 < 32) ? bqT : ckT;
            const int    ch       = (ch0 & 31) + l15;
            const float  bias     = bias_arr[ch];
            #pragma unroll
            for (int nf = 0; nf < 2; ++nf) {
                #pragma unroll
                for (int r = 0; r < 4; ++r) {
                    const int pos = pos_b + nf*16 + r;
                    outp[((size_t)n*NHW + pos)*CQK + ch] =
                        (_Float16)(acc[t][nf][r] + bias);
                }
            }
        } else {
            const int ch   = ch0 - 64 + l15;
            const float bias = d_b[ch];
            #pragma unroll
            for (int nf = 0; nf < 2; ++nf) {
                hv4 v = { (_Float16)(acc[t][nf][0] + bias),
                          (_Float16)(acc[t][nf][1] + bias),
                          (_Float16)(acc[t][nf][2] + bias),
                          (_Float16)(acc[t][nf][3] + bias) };
                *reinterpret_cast<hv4*>(
                    dv + ((size_t)n*CCH + ch)*NHW + pos_b + nf*16) = v;
            }
        }
    }
}

// ---------------------------------------------------------------------------
// Pass A: per-q-row max of S = Q K^T (same fp16 MFMA products as pass B).
// Grid: 4n x 64qt x 4 k-splits = 1024. atomicMax (uint-encoded) into m_enc.
// ---------------------------------------------------------------------------
__global__ __launch_bounds__(256) void rowmax_kernel(
    const _Float16* __restrict__ bqT, const _Float16* __restrict__ ckT,
    unsigned* __restrict__ m_enc)
{
    const int bx   = blockIdx.x;
    const int n    = bx >> 8;
    const int qt   = (bx >> 2) & 63;
    const int ks   = bx & 3;
    const int q0   = qt << 6;
    const int tid  = threadIdx.x;
    const int wave = tid >> 6;
    const int lane = tid & 63;
    const int l15  = lane & 15;
    const int quad = lane >> 4;

    const f32x4 zf = {0.f, 0.f, 0.f, 0.f};
    const hv8 qf = *reinterpret_cast<const hv8*>(
        bqT + ((size_t)n*NHW + q0 + wave*16 + l15)*CQK + quad*8);

    float mx[4] = {-1e30f, -1e30f, -1e30f, -1e30f};

    for (int kt = ks*16; kt < ks*16 + 16; ++kt) {
        const int k0 = kt << 6;
        f32x4 s[4];
        #pragma unroll
        for (int f = 0; f < 4; ++f) {
            hv8 kf = *reinterpret_cast<const hv8*>(
                ckT + ((size_t)n*NHW + k0 + f*16 + l15)*CQK + quad*8);
            s[f] = __builtin_amdgcn_mfma_f32_16x16x32_f16(qf, kf, zf, 0, 0, 0);
        }
        #pragma unroll
        for (int r = 0; r < 4; ++r)
            mx[r] = fmaxf(mx[r], fmaxf(fmaxf(s[0][r], s[1][r]),
                                        fmaxf(s[2][r], s[3][r])));
    }
    #pragma unroll
    for (int r = 0; r < 4; ++r) {
        float v = mx[r];
        v = fmaxf(v, __shfl_xor(v, 1, 64));
        v = fmaxf(v, __shfl_xor(v, 2, 64));
        v = fmaxf(v, __shfl_xor(v, 4, 64));
        v = fmaxf(v, __shfl_xor(v, 8, 64));
        mx[r] = v;
    }
    if (l15 == 0) {
        #pragma unroll
        for (int r = 0; r < 4; ++r)
            atomicMax(&m_enc[n*NHW + q0 + wave*16 + quad*4 + r], enc_f32(mx[r]));
    }
}

// ---------------------------------------------------------------------------
// Pass B: flash attention, fixed row max, CO-SPLIT 2 (was 4): each block does
// 64 q x 128 co, so QK+exp runs 2x total instead of 4x. Grid: 4n x 2cg x 64qt
// = 512. Direct float4 epilogue (acc rows are 4 consecutive q per lane; no
// LDS transpose needed; acc_l is q-indexed per lane already).
// ---------------------------------------------------------------------------
__global__ __launch_bounds__(256) void attn_kernel(
    const _Float16* __restrict__ bqT, const _Float16* __restrict__ ckT,
    const _Float16* __restrict__ dv, const unsigned* __restrict__ m_enc,
    const float* __restrict__ a, const float* __restrict__ alpha_p,
    float* __restrict__ out)
{
    __shared__ _Float16 dv_lds[128 * 72];    // V tile [128co][64k]+8 pad, 18.4 KB
    __shared__ _Float16 p_lds[4][16 * 72];   // per-wave P round-trip, 9.2 KB

    const int bx   = blockIdx.x;
    const int n    = bx >> 7;
    const int cg   = (bx >> 6) & 1;
    const int q0   = (bx & 63) << 6;
    const int co0  = cg << 7;
    const int tid  = threadIdx.x;
    const int wave = tid >> 6;
    const int lane = tid & 63;
    const int l15  = lane & 15;
    const int quad = lane >> 4;

    const f32x4 zf = {0.f, 0.f, 0.f, 0.f};
    const float L2E = 1.4426950408889634f;
    const _Float16 one_h = (_Float16)1.0f;
    const hv8 ones = { one_h, one_h, one_h, one_h, one_h, one_h, one_h, one_h };

    const hv8 qf = *reinterpret_cast<const hv8*>(
        bqT + ((size_t)n*NHW + q0 + wave*16 + l15)*CQK + quad*8);

    // fixed per-row max, prescaled for exp2
    float mneg[4];
    #pragma unroll
    for (int r = 0; r < 4; ++r)
        mneg[r] = -L2E * dec_f32(m_enc[n*NHW + q0 + wave*16 + quad*4 + r]);

    f32x4 acc[8];
    #pragma unroll
    for (int t = 0; t < 8; ++t) acc[t] = zf;
    f32x4 acc_l = zf;                       // softmax denominator per q-row

    const int co_s = tid >> 3;          // 0..31
    const int c8_s = (tid & 7) << 3;    // 0..56

    for (int kt = 0; kt < 64; ++kt) {
        const int k0 = kt << 6;
        __syncthreads();   // previous iteration's dv_lds readers done
        #pragma unroll
        for (int p = 0; p < 4; ++p) {
            int co = co_s + (p << 5);
            *reinterpret_cast<int4*>(&dv_lds[co*72 + c8_s]) =
                *reinterpret_cast<const int4*>(
                    dv + ((size_t)n*CCH + co0 + co)*NHW + k0 + c8_s);
        }
        __syncthreads();

        // ---- S = Q K^T (C/D: row=quad*4+r -> q, col=l15 -> key)
        f32x4 s[4];
        #pragma unroll
        for (int f = 0; f < 4; ++f) {
            hv8 kf = *reinterpret_cast<const hv8*>(
                ckT + ((size_t)n*NHW + k0 + f*16 + l15)*CQK + quad*8);
            s[f] = __builtin_amdgcn_mfma_f32_16x16x32_f16(qf, kf, zf, 0, 0, 0);
        }

        // ---- p = exp2(s*log2e - m*log2e), fixed m
        #pragma unroll
        for (int f = 0; f < 4; ++f) {
            #pragma unroll
            for (int r = 0; r < 4; ++r) {
                float p = exp2f(fmaf(s[f][r], L2E, mneg[r]));
                p_lds[wave][(quad*4 + r)*72 + f*16 + l15] = (_Float16)p;
            }
        }

        // ---- P: C/D layout -> A layout via per-wave LDS round-trip
        hv8 pf0 = *reinterpret_cast<const hv8*>(&p_lds[wave][l15*72 + quad*8]);
        hv8 pf1 = *reinterpret_cast<const hv8*>(&p_lds[wave][l15*72 + 32 + quad*8]);

        // ---- O[q][co] += P V^T : 8 co-frags x 2 key-halves
        #pragma unroll
        for (int t = 0; t < 8; ++t) {
            hv8 d0 = *reinterpret_cast<const hv8*>(&dv_lds[(t*16 + l15)*72 + quad*8]);
            acc[t] = __builtin_amdgcn_mfma_f32_16x16x32_f16(pf0, d0, acc[t], 0, 0, 0);
            hv8 d1 = *reinterpret_cast<const hv8*>(&dv_lds[(t*16 + l15)*72 + 32 + quad*8]);
            acc[t] = __builtin_amdgcn_mfma_f32_16x16x32_f16(pf1, d1, acc[t], 0, 0, 0);
        }
        // ---- l[q] += rowsum(P) via ones-column MFMA
        acc_l = __builtin_amdgcn_mfma_f32_16x16x32_f16(pf0, ones, acc_l, 0, 0, 0);
        acc_l = __builtin_amdgcn_mfma_f32_16x16x32_f16(pf1, ones, acc_l, 0, 0, 0);
    }

    // ---- epilogue: out[co][q..q+3] = alpha*O/l + a, direct float4 per lane
    const float alpha = alpha_p[0];
    f32x4 rl;
    #pragma unroll
    for (int r = 0; r < 4; ++r) rl[r] = alpha / acc_l[r];

    const int qv = q0 + wave*16 + quad*4;
    #pragma unroll
    for (int t = 0; t < 8; ++t) {
        const int co = co0 + t*16 + l15;
        const size_t off = ((size_t)n*CCH + co)*NHW + qv;
        float4 av = *reinterpret_cast<const float4*>(a + off);
        float4 o;
        o.x = acc[t][0]*rl[0] + av.x;
        o.y = acc[t][1]*rl[1] + av.y;
        o.z = acc[t][2]*rl[2] + av.z;
        o.w = acc[t][3]*rl[3] + av.w;
        *reinterpret_cast<float4*>(out + off) = o;
    }
}

extern "C" void kernel_launch(void* const* d_in, const int* in_sizes, int n_in,
                              void* d_out, int out_size, void* d_ws, size_t ws_size,
                              hipStream_t stream)
{
    const float* a    = (const float*)d_in[0];
    const float* b_w  = (const float*)d_in[1];
    const float* b_b  = (const float*)d_in[2];
    const float* c_w  = (const float*)d_in[3];
    const float* c_b  = (const float*)d_in[4];
    const float* d_w  = (const float*)d_in[5];
    const float* d_b  = (const float*)d_in[6];
    const float* alp  = (const float*)d_in[7];
    float* out = (float*)d_out;

    _Float16* bqT  = (_Float16*)d_ws;                 // [4][4096][32] fp16, 1 MB
    _Float16* ckT  = bqT + (size_t)4*NHW*CQK;         // [4][4096][32] fp16, 1 MB
    _Float16* dv   = ckT + (size_t)4*NHW*CQK;         // [4][256][4096] fp16, 8 MB
    unsigned* m_enc = (unsigned*)(dv + (size_t)4*CCH*NHW);  // [4][4096] u32, 64 KB
    _Float16* Wh   = (_Float16*)(m_enc + 4*NHW);      // [320][256] fp16, 160 KB

    prep_kernel<<<144, 256, 0, stream>>>(b_w, c_w, d_w, Wh, m_enc);
    proj_kernel<<<512, 256, 0, stream>>>(a, Wh, b_b, c_b, d_b, bqT, ckT, dv);
    rowmax_kernel<<<1024, 256, 0, stream>>>(bqT, ckT, m_enc);
    attn_kernel<<<512, 256, 0, stream>>>(bqT, ckT, dv, m_enc, a, alp, out);
}

// Round 7
// 241.928 us; speedup vs baseline: 1.3367x; 1.3367x over previous
//
#include <hip/hip_runtime.h>
#include <hip/hip_bf16.h>

#define CCH 256
#define CQK 32
#define NHW 4096

typedef float f32x4 __attribute__((ext_vector_type(4)));
typedef _Float16 hv8 __attribute__((ext_vector_type(8)));
typedef _Float16 hv4 __attribute__((ext_vector_type(4)));

// Monotone float<->uint encoding so float max == uint max (handles negatives).
__device__ __forceinline__ unsigned enc_f32(float f) {
    unsigned u = __float_as_uint(f);
    return (u & 0x80000000u) ? ~u : (u | 0x80000000u);
}
__device__ __forceinline__ float dec_f32(unsigned u) {
    return __uint_as_float((u & 0x80000000u) ? (u ^ 0x80000000u) : ~u);
}

// ---------------------------------------------------------------------------
// Prep kernel: (a) convert Wall = concat(b_w, c_w, d_w) fp32 -> fp16 [320][256];
// (b) init m_enc = 0. Grid 144 x 256.
// ---------------------------------------------------------------------------
__global__ __launch_bounds__(256) void prep_kernel(
    const float* __restrict__ b_w, const float* __restrict__ c_w,
    const float* __restrict__ d_w, _Float16* __restrict__ Wh,
    unsigned* __restrict__ m_enc)
{
    const int bid = blockIdx.x, tid = threadIdx.x;
    if (bid < 80) {
        const int idx = (bid * 256 + tid) * 4;
        const int row = idx >> 8, col = idx & 255;
        const float* src = (row < 32) ? (b_w + row * CCH + col)
                         : (row < 64) ? (c_w + (row - 32) * CCH + col)
                                      : (d_w + (row - 64) * CCH + col);
        float4 v = *reinterpret_cast<const float4*>(src);
        _Float16* dst = Wh + (size_t)row * CCH + col;
        dst[0] = (_Float16)v.x; dst[1] = (_Float16)v.y;
        dst[2] = (_Float16)v.z; dst[3] = (_Float16)v.w;
    } else {
        m_enc[(bid - 80) * 256 + tid] = 0u;
    }
}

// ---------------------------------------------------------------------------
// Projection kernel (round-6 verified). D[m=pos][n=ch]: A-frags from aT (pos),
// B-frags from Wh (ch_out). C/D: row=quad*4+r -> pos, col=l15 -> ch.
// dv stores are packed 8 B (4 consecutive positions per lane).
// Grid: 4 batches x 128 position-tiles of 32. Block 256 = 4 waves.
// ---------------------------------------------------------------------------
__global__ __launch_bounds__(256) void proj_kernel(
    const float* __restrict__ a, const _Float16* __restrict__ Wh,
    const float* __restrict__ b_b, const float* __restrict__ c_b,
    const float* __restrict__ d_b,
    _Float16* __restrict__ bqT, _Float16* __restrict__ ckT,
    _Float16* __restrict__ dv)
{
    __shared__ _Float16 aT[32][CCH + 24];   // [pos][ch]; stride 560 B (16B-mult)

    const int n    = blockIdx.x >> 7;
    const int i0   = (blockIdx.x & 127) << 5;
    const int tid  = threadIdx.x;
    const int lane = tid & 63;
    const int wave = tid >> 6;
    const int l15  = lane & 15;
    const int quad = lane >> 4;

    // stage a^T tile: thread handles channel c = tid, 32 positions
    {
        const float* ap = a + (size_t)(n*CCH + tid)*NHW + i0;
        #pragma unroll
        for (int j = 0; j < 8; ++j) {
            float4 v = *reinterpret_cast<const float4*>(ap + j*4);
            aT[j*4+0][tid] = (_Float16)v.x;
            aT[j*4+1][tid] = (_Float16)v.y;
            aT[j*4+2][tid] = (_Float16)v.z;
            aT[j*4+3][tid] = (_Float16)v.w;
        }
    }
    __syncthreads();

    const f32x4 zf = {0.f, 0.f, 0.f, 0.f};
    f32x4 acc[5][2];
    #pragma unroll
    for (int t = 0; t < 5; ++t) { acc[t][0] = zf; acc[t][1] = zf; }

    const int ch0w = wave * 80;

    #pragma unroll
    for (int ks = 0; ks < 8; ++ks) {
        const int k0 = ks * 32;
        hv8 af0 = *reinterpret_cast<const hv8*>(&aT[l15][k0 + quad*8]);
        hv8 af1 = *reinterpret_cast<const hv8*>(&aT[16 + l15][k0 + quad*8]);
        #pragma unroll
        for (int t = 0; t < 5; ++t) {
            const int ch0 = ch0w + t*16;
            hv8 bf = *reinterpret_cast<const hv8*>(
                Wh + (size_t)(ch0 + l15)*CCH + k0 + quad*8);
            acc[t][0] = __builtin_amdgcn_mfma_f32_16x16x32_f16(af0, bf, acc[t][0], 0, 0, 0);
            acc[t][1] = __builtin_amdgcn_mfma_f32_16x16x32_f16(af1, bf, acc[t][1], 0, 0, 0);
        }
    }

    // epilogue: row = quad*4+r -> pos, col = l15 -> ch
    const int pos_b = i0 + quad*4;
    #pragma unroll
    for (int t = 0; t < 5; ++t) {
        const int ch0 = ch0w + t*16;
        if (ch0 < 64) {
            const float* bias_arr = (ch0 < 32) ? b_b : c_b;
            _Float16*    outp     = (ch0 < 32) ? bqT : ckT;
            const int    ch       = (ch0 & 31) + l15;
            const float  bias     = bias_arr[ch];
            #pragma unroll
            for (int nf = 0; nf < 2; ++nf) {
                #pragma unroll
                for (int r = 0; r < 4; ++r) {
                    const int pos = pos_b + nf*16 + r;
                    outp[((size_t)n*NHW + pos)*CQK + ch] =
                        (_Float16)(acc[t][nf][r] + bias);
                }
            }
        } else {
            const int ch   = ch0 - 64 + l15;
            const float bias = d_b[ch];
            #pragma unroll
            for (int nf = 0; nf < 2; ++nf) {
                hv4 v = { (_Float16)(acc[t][nf][0] + bias),
                          (_Float16)(acc[t][nf][1] + bias),
                          (_Float16)(acc[t][nf][2] + bias),
                          (_Float16)(acc[t][nf][3] + bias) };
                *reinterpret_cast<hv4*>(
                    dv + ((size_t)n*CCH + ch)*NHW + pos_b + nf*16) = v;
            }
        }
    }
}

// ---------------------------------------------------------------------------
// Pass A: per-q-row max of S = Q K^T (same fp16 MFMA products as pass B).
// Grid: 4n x 64qt x 4 k-splits = 1024. atomicMax (uint-encoded) into m_enc.
// ---------------------------------------------------------------------------
__global__ __launch_bounds__(256) void rowmax_kernel(
    const _Float16* __restrict__ bqT, const _Float16* __restrict__ ckT,
    unsigned* __restrict__ m_enc)
{
    const int bx   = blockIdx.x;
    const int n    = bx >> 8;
    const int qt   = (bx >> 2) & 63;
    const int ks   = bx & 3;
    const int q0   = qt << 6;
    const int tid  = threadIdx.x;
    const int wave = tid >> 6;
    const int lane = tid & 63;
    const int l15  = lane & 15;
    const int quad = lane >> 4;

    const f32x4 zf = {0.f, 0.f, 0.f, 0.f};
    const hv8 qf = *reinterpret_cast<const hv8*>(
        bqT + ((size_t)n*NHW + q0 + wave*16 + l15)*CQK + quad*8);

    float mx[4] = {-1e30f, -1e30f, -1e30f, -1e30f};

    for (int kt = ks*16; kt < ks*16 + 16; ++kt) {
        const int k0 = kt << 6;
        f32x4 s[4];
        #pragma unroll
        for (int f = 0; f < 4; ++f) {
            hv8 kf = *reinterpret_cast<const hv8*>(
                ckT + ((size_t)n*NHW + k0 + f*16 + l15)*CQK + quad*8);
            s[f] = __builtin_amdgcn_mfma_f32_16x16x32_f16(qf, kf, zf, 0, 0, 0);
        }
        #pragma unroll
        for (int r = 0; r < 4; ++r)
            mx[r] = fmaxf(mx[r], fmaxf(fmaxf(s[0][r], s[1][r]),
                                        fmaxf(s[2][r], s[3][r])));
    }
    #pragma unroll
    for (int r = 0; r < 4; ++r) {
        float v = mx[r];
        v = fmaxf(v, __shfl_xor(v, 1, 64));
        v = fmaxf(v, __shfl_xor(v, 2, 64));
        v = fmaxf(v, __shfl_xor(v, 4, 64));
        v = fmaxf(v, __shfl_xor(v, 8, 64));
        mx[r] = v;
    }
    if (l15 == 0) {
        #pragma unroll
        for (int r = 0; r < 4; ++r)
            atomicMax(&m_enc[n*NHW + q0 + wave*16 + quad*4 + r], enc_f32(mx[r]));
    }
}

// ---------------------------------------------------------------------------
// Pass B: flash attention, fixed row max. CO-SPLIT 4 (round-5 config: grid
// 1024 = 4 blocks/CU — round 6 proved 2 blocks/CU starves latency hiding).
// Double-buffered V tile: prefetch tile k+1 into registers at iteration top,
// write to the alternate LDS buffer at the bottom -> ONE barrier per iter.
// Direct float4 epilogue (acc rows are 4 consecutive q per lane).
// ---------------------------------------------------------------------------
__global__ __launch_bounds__(256) void attn_kernel(
    const _Float16* __restrict__ bqT, const _Float16* __restrict__ ckT,
    const _Float16* __restrict__ dv, const unsigned* __restrict__ m_enc,
    const float* __restrict__ a, const float* __restrict__ alpha_p,
    float* __restrict__ out)
{
    __shared__ _Float16 dv_lds[2][64 * 72];  // V tiles [64co][64k]+8 pad, 2x9 KB
    __shared__ _Float16 p_lds[4][16 * 72];   // per-wave P round-trip, 9 KB

    const int bx   = blockIdx.x;
    const int n    = bx >> 8;
    const int cg   = (bx >> 6) & 3;
    const int q0   = (bx & 63) << 6;
    const int co0  = cg << 6;
    const int tid  = threadIdx.x;
    const int wave = tid >> 6;
    const int lane = tid & 63;
    const int l15  = lane & 15;
    const int quad = lane >> 4;

    const f32x4 zf = {0.f, 0.f, 0.f, 0.f};
    const float L2E = 1.4426950408889634f;
    const _Float16 one_h = (_Float16)1.0f;
    const hv8 ones = { one_h, one_h, one_h, one_h, one_h, one_h, one_h, one_h };

    const hv8 qf = *reinterpret_cast<const hv8*>(
        bqT + ((size_t)n*NHW + q0 + wave*16 + l15)*CQK + quad*8);

    // fixed per-row max, prescaled for exp2
    float mneg[4];
    #pragma unroll
    for (int r = 0; r < 4; ++r)
        mneg[r] = -L2E * dec_f32(m_enc[n*NHW + q0 + wave*16 + quad*4 + r]);

    f32x4 acc[4];
    #pragma unroll
    for (int t = 0; t < 4; ++t) acc[t] = zf;
    f32x4 acc_l = zf;                       // softmax denominator per q-row

    // staging map: thread -> (co row pair, 16 B segment)
    const int co_s = tid >> 3;          // 0..31
    const int c8_s = (tid & 7) << 3;    // 0..56
    const _Float16* dvs0 = dv + ((size_t)(n*CCH + co0 + co_s))*NHW + c8_s;
    const _Float16* dvs1 = dvs0 + (size_t)32 * NHW;

    // prologue: tile 0 -> buf 0
    {
        int4 r0 = *reinterpret_cast<const int4*>(dvs0);
        int4 r1 = *reinterpret_cast<const int4*>(dvs1);
        *reinterpret_cast<int4*>(&dv_lds[0][co_s*72 + c8_s])        = r0;
        *reinterpret_cast<int4*>(&dv_lds[0][(co_s + 32)*72 + c8_s]) = r1;
    }
    __syncthreads();

    for (int kt = 0; kt < 64; ++kt) {
        const int k0 = kt << 6;
        const int cur = kt & 1;

        // prefetch next tile into registers (overlaps all compute below)
        int4 nr0, nr1;
        if (kt < 63) {
            nr0 = *reinterpret_cast<const int4*>(dvs0 + k0 + 64);
            nr1 = *reinterpret_cast<const int4*>(dvs1 + k0 + 64);
        }

        // ---- S = Q K^T (C/D: row=quad*4+r -> q, col=l15 -> key)
        f32x4 s[4];
        #pragma unroll
        for (int f = 0; f < 4; ++f) {
            hv8 kf = *reinterpret_cast<const hv8*>(
                ckT + ((size_t)n*NHW + k0 + f*16 + l15)*CQK + quad*8);
            s[f] = __builtin_amdgcn_mfma_f32_16x16x32_f16(qf, kf, zf, 0, 0, 0);
        }

        // ---- p = exp2(s*log2e - m*log2e), fixed m
        #pragma unroll
        for (int f = 0; f < 4; ++f) {
            #pragma unroll
            for (int r = 0; r < 4; ++r) {
                float p = exp2f(fmaf(s[f][r], L2E, mneg[r]));
                p_lds[wave][(quad*4 + r)*72 + f*16 + l15] = (_Float16)p;
            }
        }

        // ---- P: C/D layout -> A layout via per-wave LDS round-trip
        // (same-wave write->read; compiler inserts lgkmcnt, no barrier needed)
        hv8 pf0 = *reinterpret_cast<const hv8*>(&p_lds[wave][l15*72 + quad*8]);
        hv8 pf1 = *reinterpret_cast<const hv8*>(&p_lds[wave][l15*72 + 32 + quad*8]);

        // ---- O[q][co] += P V^T : 4 co-frags x 2 key-halves
        #pragma unroll
        for (int t = 0; t < 4; ++t) {
            hv8 d0 = *reinterpret_cast<const hv8*>(&dv_lds[cur][(t*16 + l15)*72 + quad*8]);
            acc[t] = __builtin_amdgcn_mfma_f32_16x16x32_f16(pf0, d0, acc[t], 0, 0, 0);
            hv8 d1 = *reinterpret_cast<const hv8*>(&dv_lds[cur][(t*16 + l15)*72 + 32 + quad*8]);
            acc[t] = __builtin_amdgcn_mfma_f32_16x16x32_f16(pf1, d1, acc[t], 0, 0, 0);
        }
        // ---- l[q] += rowsum(P) via ones-column MFMA
        acc_l = __builtin_amdgcn_mfma_f32_16x16x32_f16(pf0, ones, acc_l, 0, 0, 0);
        acc_l = __builtin_amdgcn_mfma_f32_16x16x32_f16(pf1, ones, acc_l, 0, 0, 0);

        // ---- write prefetched tile to the alternate buffer, single barrier
        if (kt < 63) {
            *reinterpret_cast<int4*>(&dv_lds[cur ^ 1][co_s*72 + c8_s])        = nr0;
            *reinterpret_cast<int4*>(&dv_lds[cur ^ 1][(co_s + 32)*72 + c8_s]) = nr1;
            __syncthreads();
        }
    }

    // ---- epilogue: out[co][q..q+3] = alpha*O/l + a, direct float4 per lane
    const float alpha = alpha_p[0];
    f32x4 rl;
    #pragma unroll
    for (int r = 0; r < 4; ++r) rl[r] = alpha / acc_l[r];

    const int qv = q0 + wave*16 + quad*4;
    #pragma unroll
    for (int t = 0; t < 4; ++t) {
        const int co = co0 + t*16 + l15;
        const size_t off = ((size_t)n*CCH + co)*NHW + qv;
        float4 av = *reinterpret_cast<const float4*>(a + off);
        float4 o;
        o.x = acc[t][0]*rl[0] + av.x;
        o.y = acc[t][1]*rl[1] + av.y;
        o.z = acc[t][2]*rl[2] + av.z;
        o.w = acc[t][3]*rl[3] + av.w;
        *reinterpret_cast<float4*>(out + off) = o;
    }
}

extern "C" void kernel_launch(void* const* d_in, const int* in_sizes, int n_in,
                              void* d_out, int out_size, void* d_ws, size_t ws_size,
                              hipStream_t stream)
{
    const float* a    = (const float*)d_in[0];
    const float* b_w  = (const float*)d_in[1];
    const float* b_b  = (const float*)d_in[2];
    const float* c_w  = (const float*)d_in[3];
    const float* c_b  = (const float*)d_in[4];
    const float* d_w  = (const float*)d_in[5];
    const float* d_b  = (const float*)d_in[6];
    const float* alp  = (const float*)d_in[7];
    float* out = (float*)d_out;

    _Float16* bqT  = (_Float16*)d_ws;                 // [4][4096][32] fp16, 1 MB
    _Float16* ckT  = bqT + (size_t)4*NHW*CQK;         // [4][4096][32] fp16, 1 MB
    _Float16* dv   = ckT + (size_t)4*NHW*CQK;         // [4][256][4096] fp16, 8 MB
    unsigned* m_enc = (unsigned*)(dv + (size_t)4*CCH*NHW);  // [4][4096] u32, 64 KB
    _Float16* Wh   = (_Float16*)(m_enc + 4*NHW);      // [320][256] fp16, 160 KB

    prep_kernel<<<144, 256, 0, stream>>>(b_w, c_w, d_w, Wh, m_enc);
    proj_kernel<<<512, 256, 0, stream>>>(a, Wh, b_b, c_b, d_b, bqT, ckT, dv);
    rowmax_kernel<<<1024, 256, 0, stream>>>(bqT, ckT, m_enc);
    attn_kernel<<<1024, 256, 0, stream>>>(bqT, ckT, dv, m_enc, a, alp, out);
}

// Round 9
// 214.426 us; speedup vs baseline: 1.5081x; 1.1283x over previous
//
#include <hip/hip_runtime.h>
#include <hip/hip_bf16.h>

#define CCH 256
#define CQK 32
#define NHW 4096

typedef float f32x4 __attribute__((ext_vector_type(4)));
typedef _Float16 hv8 __attribute__((ext_vector_type(8)));
typedef _Float16 hv4 __attribute__((ext_vector_type(4)));
typedef __fp16 fv2 __attribute__((ext_vector_type(2)));   // cvt_pkrtz native type

// Monotone float<->uint encoding so float max == uint max (handles negatives).
__device__ __forceinline__ unsigned enc_f32(float f) {
    unsigned u = __float_as_uint(f);
    return (u & 0x80000000u) ? ~u : (u | 0x80000000u);
}
__device__ __forceinline__ float dec_f32(unsigned u) {
    return __uint_as_float((u & 0x80000000u) ? (u ^ 0x80000000u) : ~u);
}

// ---------------------------------------------------------------------------
// Prep kernel: (a) convert Wall = concat(b_w, c_w, d_w) fp32 -> fp16 [320][256];
// (b) init m_enc = 0. Grid 144 x 256.
// ---------------------------------------------------------------------------
__global__ __launch_bounds__(256) void prep_kernel(
    const float* __restrict__ b_w, const float* __restrict__ c_w,
    const float* __restrict__ d_w, _Float16* __restrict__ Wh,
    unsigned* __restrict__ m_enc)
{
    const int bid = blockIdx.x, tid = threadIdx.x;
    if (bid < 80) {
        const int idx = (bid * 256 + tid) * 4;
        const int row = idx >> 8, col = idx & 255;
        const float* src = (row < 32) ? (b_w + row * CCH + col)
                         : (row < 64) ? (c_w + (row - 32) * CCH + col)
                                      : (d_w + (row - 64) * CCH + col);
        float4 v = *reinterpret_cast<const float4*>(src);
        _Float16* dst = Wh + (size_t)row * CCH + col;
        dst[0] = (_Float16)v.x; dst[1] = (_Float16)v.y;
        dst[2] = (_Float16)v.z; dst[3] = (_Float16)v.w;
    } else {
        m_enc[(bid - 80) * 256 + tid] = 0u;
    }
}

// ---------------------------------------------------------------------------
// Projection kernel (round-6/7 verified, unchanged). D[m=pos][n=ch].
// Grid: 4 batches x 128 position-tiles of 32. Block 256 = 4 waves.
// ---------------------------------------------------------------------------
__global__ __launch_bounds__(256) void proj_kernel(
    const float* __restrict__ a, const _Float16* __restrict__ Wh,
    const float* __restrict__ b_b, const float* __restrict__ c_b,
    const float* __restrict__ d_b,
    _Float16* __restrict__ bqT, _Float16* __restrict__ ckT,
    _Float16* __restrict__ dv)
{
    __shared__ _Float16 aT[32][CCH + 24];   // [pos][ch]; stride 560 B (16B-mult)

    const int n    = blockIdx.x >> 7;
    const int i0   = (blockIdx.x & 127) << 5;
    const int tid  = threadIdx.x;
    const int lane = tid & 63;
    const int wave = tid >> 6;
    const int l15  = lane & 15;
    const int quad = lane >> 4;

    {
        const float* ap = a + (size_t)(n*CCH + tid)*NHW + i0;
        #pragma unroll
        for (int j = 0; j < 8; ++j) {
            float4 v = *reinterpret_cast<const float4*>(ap + j*4);
            aT[j*4+0][tid] = (_Float16)v.x;
            aT[j*4+1][tid] = (_Float16)v.y;
            aT[j*4+2][tid] = (_Float16)v.z;
            aT[j*4+3][tid] = (_Float16)v.w;
        }
    }
    __syncthreads();

    const f32x4 zf = {0.f, 0.f, 0.f, 0.f};
    f32x4 acc[5][2];
    #pragma unroll
    for (int t = 0; t < 5; ++t) { acc[t][0] = zf; acc[t][1] = zf; }

    const int ch0w = wave * 80;

    #pragma unroll
    for (int ks = 0; ks < 8; ++ks) {
        const int k0 = ks * 32;
        hv8 af0 = *reinterpret_cast<const hv8*>(&aT[l15][k0 + quad*8]);
        hv8 af1 = *reinterpret_cast<const hv8*>(&aT[16 + l15][k0 + quad*8]);
        #pragma unroll
        for (int t = 0; t < 5; ++t) {
            const int ch0 = ch0w + t*16;
            hv8 bf = *reinterpret_cast<const hv8*>(
                Wh + (size_t)(ch0 + l15)*CCH + k0 + quad*8);
            acc[t][0] = __builtin_amdgcn_mfma_f32_16x16x32_f16(af0, bf, acc[t][0], 0, 0, 0);
            acc[t][1] = __builtin_amdgcn_mfma_f32_16x16x32_f16(af1, bf, acc[t][1], 0, 0, 0);
        }
    }

    const int pos_b = i0 + quad*4;
    #pragma unroll
    for (int t = 0; t < 5; ++t) {
        const int ch0 = ch0w + t*16;
        if (ch0 < 64) {
            const float* bias_arr = (ch0 < 32) ? b_b : c_b;
            _Float16*    outp     = (ch0 < 32) ? bqT : ckT;
            const int    ch       = (ch0 & 31) + l15;
            const float  bias     = bias_arr[ch];
            #pragma unroll
            for (int nf = 0; nf < 2; ++nf) {
                #pragma unroll
                for (int r = 0; r < 4; ++r) {
                    const int pos = pos_b + nf*16 + r;
                    outp[((size_t)n*NHW + pos)*CQK + ch] =
                        (_Float16)(acc[t][nf][r] + bias);
                }
            }
        } else {
            const int ch   = ch0 - 64 + l15;
            const float bias = d_b[ch];
            #pragma unroll
            for (int nf = 0; nf < 2; ++nf) {
                hv4 v = { (_Float16)(acc[t][nf][0] + bias),
                          (_Float16)(acc[t][nf][1] + bias),
                          (_Float16)(acc[t][nf][2] + bias),
                          (_Float16)(acc[t][nf][3] + bias) };
                *reinterpret_cast<hv4*>(
                    dv + ((size_t)n*CCH + ch)*NHW + pos_b + nf*16) = v;
            }
        }
    }
}

// ---------------------------------------------------------------------------
// Pass A: per-q-row max, TRANSPOSED S^T = K Q^T (same loads as before, operand
// order mirrored — round-6-proj-verified pattern). Lane (quad,l15) reg (f,r)
// holds S[q=l15][key=f*16+quad*4+r] -> max over keys is in-lane over f,r then
// 2 shuffles across quads. Grid: 4n x 64qt x 4 k-splits = 1024.
// ---------------------------------------------------------------------------
__global__ __launch_bounds__(256) void rowmax_kernel(
    const _Float16* __restrict__ bqT, const _Float16* __restrict__ ckT,
    unsigned* __restrict__ m_enc)
{
    const int bx   = blockIdx.x;
    const int n    = bx >> 8;
    const int qt   = (bx >> 2) & 63;
    const int ks   = bx & 3;
    const int q0   = qt << 6;
    const int tid  = threadIdx.x;
    const int wave = tid >> 6;
    const int lane = tid & 63;
    const int l15  = lane & 15;
    const int quad = lane >> 4;

    const f32x4 zf = {0.f, 0.f, 0.f, 0.f};
    const hv8 qf = *reinterpret_cast<const hv8*>(
        bqT + ((size_t)n*NHW + q0 + wave*16 + l15)*CQK + quad*8);

    float mx = -1e30f;

    for (int kt = ks*16; kt < ks*16 + 16; ++kt) {
        const int k0 = kt << 6;
        #pragma unroll
        for (int f = 0; f < 4; ++f) {
            hv8 kf = *reinterpret_cast<const hv8*>(
                ckT + ((size_t)n*NHW + k0 + f*16 + l15)*CQK + quad*8);
            f32x4 s = __builtin_amdgcn_mfma_f32_16x16x32_f16(kf, qf, zf, 0, 0, 0);
            mx = fmaxf(mx, fmaxf(fmaxf(s[0], s[1]), fmaxf(s[2], s[3])));
        }
    }
    // reduce across quads (same l15 = same q)
    mx = fmaxf(mx, __shfl_xor(mx, 16, 64));
    mx = fmaxf(mx, __shfl_xor(mx, 32, 64));
    if (lane < 16)
        atomicMax(&m_enc[n*NHW + q0 + wave*16 + l15], enc_f32(mx));
}

// ---------------------------------------------------------------------------
// Pass B: flash attention, fixed row max, co-split 4 (grid 1024 = 4 blocks/CU),
// one-barrier double-buffered V tile, direct float4 epilogue.
// QK computed TRANSPOSED (S^T = K Q^T): lane holds 4 consecutive keys for one
// q (=l15), so m is a single scalar per lane and p-writes are pk-cvt + b64.
// exp via __builtin_amdgcn_exp2f (raw v_exp_f32 — libm exp2f was ~10 instrs).
// ---------------------------------------------------------------------------
__global__ __launch_bounds__(256) void attn_kernel(
    const _Float16* __restrict__ bqT, const _Float16* __restrict__ ckT,
    const _Float16* __restrict__ dv, const unsigned* __restrict__ m_enc,
    const float* __restrict__ a, const float* __restrict__ alpha_p,
    float* __restrict__ out)
{
    __shared__ _Float16 dv_lds[2][64 * 72];  // V tiles [64co][64k]+8 pad, 2x9 KB
    __shared__ _Float16 p_lds[4][16 * 72];   // per-wave P round-trip, 9 KB

    const int bx   = blockIdx.x;
    const int n    = bx >> 8;
    const int cg   = (bx >> 6) & 3;
    const int q0   = (bx & 63) << 6;
    const int co0  = cg << 6;
    const int tid  = threadIdx.x;
    const int wave = tid >> 6;
    const int lane = tid & 63;
    const int l15  = lane & 15;
    const int quad = lane >> 4;

    const f32x4 zf = {0.f, 0.f, 0.f, 0.f};
    const float L2E = 1.4426950408889634f;
    const _Float16 one_h = (_Float16)1.0f;
    const hv8 ones = { one_h, one_h, one_h, one_h, one_h, one_h, one_h, one_h };

    const hv8 qf = *reinterpret_cast<const hv8*>(
        bqT + ((size_t)n*NHW + q0 + wave*16 + l15)*CQK + quad*8);

    // fixed max for this lane's q (=l15), prescaled for exp2
    const float mneg = -L2E * dec_f32(m_enc[n*NHW + q0 + wave*16 + l15]);

    f32x4 acc[4];
    #pragma unroll
    for (int t = 0; t < 4; ++t) acc[t] = zf;
    f32x4 acc_l = zf;                       // softmax denominator per q-row

    // staging map: thread -> (co row pair, 16 B segment)
    const int co_s = tid >> 3;          // 0..31
    const int c8_s = (tid & 7) << 3;    // 0..56
    const _Float16* dvs0 = dv + ((size_t)(n*CCH + co0 + co_s))*NHW + c8_s;
    const _Float16* dvs1 = dvs0 + (size_t)32 * NHW;

    // prologue: tile 0 -> buf 0
    {
        int4 r0 = *reinterpret_cast<const int4*>(dvs0);
        int4 r1 = *reinterpret_cast<const int4*>(dvs1);
        *reinterpret_cast<int4*>(&dv_lds[0][co_s*72 + c8_s])        = r0;
        *reinterpret_cast<int4*>(&dv_lds[0][(co_s + 32)*72 + c8_s]) = r1;
    }
    __syncthreads();

    for (int kt = 0; kt < 64; ++kt) {
        const int k0 = kt << 6;
        const int cur = kt & 1;

        // prefetch next tile into registers (overlaps all compute below)
        int4 nr0, nr1;
        if (kt < 63) {
            nr0 = *reinterpret_cast<const int4*>(dvs0 + k0 + 64);
            nr1 = *reinterpret_cast<const int4*>(dvs1 + k0 + 64);
        }

        // ---- S^T = K Q^T (C/D: row=f*16+quad*4+r -> key, col=l15 -> q)
        // ---- then p = exp2(s*L2E + mneg), packed b64 write to p_lds[q][key]
        #pragma unroll
        for (int f = 0; f < 4; ++f) {
            hv8 kf = *reinterpret_cast<const hv8*>(
                ckT + ((size_t)n*NHW + k0 + f*16 + l15)*CQK + quad*8);
            f32x4 s = __builtin_amdgcn_mfma_f32_16x16x32_f16(kf, qf, zf, 0, 0, 0);
            float p0 = __builtin_amdgcn_exp2f(fmaf(s[0], L2E, mneg));
            float p1 = __builtin_amdgcn_exp2f(fmaf(s[1], L2E, mneg));
            float p2 = __builtin_amdgcn_exp2f(fmaf(s[2], L2E, mneg));
            float p3 = __builtin_amdgcn_exp2f(fmaf(s[3], L2E, mneg));
            fv2 lo = __builtin_amdgcn_cvt_pkrtz(p0, p1);
            fv2 hi = __builtin_amdgcn_cvt_pkrtz(p2, p3);
            uint2 w;
            w.x = __builtin_bit_cast(unsigned, lo);
            w.y = __builtin_bit_cast(unsigned, hi);
            *reinterpret_cast<uint2*>(
                &p_lds[wave][l15*72 + f*16 + quad*4]) = w;
        }

        // ---- P: A-operand fragments (same-wave write->read, lgkmcnt only)
        hv8 pf0 = *reinterpret_cast<const hv8*>(&p_lds[wave][l15*72 + quad*8]);
        hv8 pf1 = *reinterpret_cast<const hv8*>(&p_lds[wave][l15*72 + 32 + quad*8]);

        // ---- O[q][co] += P V^T : 4 co-frags x 2 key-halves
        #pragma unroll
        for (int t = 0; t < 4; ++t) {
            hv8 d0 = *reinterpret_cast<const hv8*>(&dv_lds[cur][(t*16 + l15)*72 + quad*8]);
            acc[t] = __builtin_amdgcn_mfma_f32_16x16x32_f16(pf0, d0, acc[t], 0, 0, 0);
            hv8 d1 = *reinterpret_cast<const hv8*>(&dv_lds[cur][(t*16 + l15)*72 + 32 + quad*8]);
            acc[t] = __builtin_amdgcn_mfma_f32_16x16x32_f16(pf1, d1, acc[t], 0, 0, 0);
        }
        // ---- l[q] += rowsum(P) via ones-column MFMA
        acc_l = __builtin_amdgcn_mfma_f32_16x16x32_f16(pf0, ones, acc_l, 0, 0, 0);
        acc_l = __builtin_amdgcn_mfma_f32_16x16x32_f16(pf1, ones, acc_l, 0, 0, 0);

        // ---- write prefetched tile to the alternate buffer, single barrier
        if (kt < 63) {
            *reinterpret_cast<int4*>(&dv_lds[cur ^ 1][co_s*72 + c8_s])        = nr0;
            *reinterpret_cast<int4*>(&dv_lds[cur ^ 1][(co_s + 32)*72 + c8_s]) = nr1;
            __syncthreads();
        }
    }

    // ---- epilogue: out[co][q..q+3] = alpha*O/l + a, direct float4 per lane
    const float alpha = alpha_p[0];
    f32x4 rl;
    #pragma unroll
    for (int r = 0; r < 4; ++r) rl[r] = alpha / acc_l[r];

    const int qv = q0 + wave*16 + quad*4;
    #pragma unroll
    for (int t = 0; t < 4; ++t) {
        const int co = co0 + t*16 + l15;
        const size_t off = ((size_t)n*CCH + co)*NHW + qv;
        float4 av = *reinterpret_cast<const float4*>(a + off);
        float4 o;
        o.x = acc[t][0]*rl[0] + av.x;
        o.y = acc[t][1]*rl[1] + av.y;
        o.z = acc[t][2]*rl[2] + av.z;
        o.w = acc[t][3]*rl[3] + av.w;
        *reinterpret_cast<float4*>(out + off) = o;
    }
}

extern "C" void kernel_launch(void* const* d_in, const int* in_sizes, int n_in,
                              void* d_out, int out_size, void* d_ws, size_t ws_size,
                              hipStream_t stream)
{
    const float* a    = (const float*)d_in[0];
    const float* b_w  = (const float*)d_in[1];
    const float* b_b  = (const float*)d_in[2];
    const float* c_w  = (const float*)d_in[3];
    const float* c_b  = (const float*)d_in[4];
    const float* d_w  = (const float*)d_in[5];
    const float* d_b  = (const float*)d_in[6];
    const float* alp  = (const float*)d_in[7];
    float* out = (float*)d_out;

    _Float16* bqT  = (_Float16*)d_ws;                 // [4][4096][32] fp16, 1 MB
    _Float16* ckT  = bqT + (size_t)4*NHW*CQK;         // [4][4096][32] fp16, 1 MB
    _Float16* dv   = ckT + (size_t)4*NHW*CQK;         // [4][256][4096] fp16, 8 MB
    unsigned* m_enc = (unsigned*)(dv + (size_t)4*CCH*NHW);  // [4][4096] u32, 64 KB
    _Float16* Wh   = (_Float16*)(m_enc + 4*NHW);      // [320][256] fp16, 160 KB

    prep_kernel<<<144, 256, 0, stream>>>(b_w, c_w, d_w, Wh, m_enc);
    proj_kernel<<<512, 256, 0, stream>>>(a, Wh, b_b, c_b, d_b, bqT, ckT, dv);
    rowmax_kernel<<<1024, 256, 0, stream>>>(bqT, ckT, m_enc);
    attn_kernel<<<1024, 256, 0, stream>>>(bqT, ckT, dv, m_enc, a, alp, out);
}

// Round 10
// 198.642 us; speedup vs baseline: 1.6280x; 1.0795x over previous
//
#include <hip/hip_runtime.h>
#include <hip/hip_bf16.h>

#define CCH 256
#define CQK 32
#define NHW 4096

typedef float f32x4 __attribute__((ext_vector_type(4)));
typedef _Float16 hv8 __attribute__((ext_vector_type(8)));
typedef _Float16 hv4 __attribute__((ext_vector_type(4)));
typedef __fp16 fv2 __attribute__((ext_vector_type(2)));   // cvt_pkrtz native type

// Monotone float<->uint encoding so float max == uint max (handles negatives).
__device__ __forceinline__ unsigned enc_f32(float f) {
    unsigned u = __float_as_uint(f);
    return (u & 0x80000000u) ? ~u : (u | 0x80000000u);
}
__device__ __forceinline__ float dec_f32(unsigned u) {
    return __uint_as_float((u & 0x80000000u) ? (u ^ 0x80000000u) : ~u);
}

// ---------------------------------------------------------------------------
// Prep kernel: (a) convert Wall = concat(b_w, c_w, d_w) fp32 -> fp16 [320][256];
// (b) init m_enc = 0. Grid 144 x 256.
// ---------------------------------------------------------------------------
__global__ __launch_bounds__(256) void prep_kernel(
    const float* __restrict__ b_w, const float* __restrict__ c_w,
    const float* __restrict__ d_w, _Float16* __restrict__ Wh,
    unsigned* __restrict__ m_enc)
{
    const int bid = blockIdx.x, tid = threadIdx.x;
    if (bid < 80) {
        const int idx = (bid * 256 + tid) * 4;
        const int row = idx >> 8, col = idx & 255;
        const float* src = (row < 32) ? (b_w + row * CCH + col)
                         : (row < 64) ? (c_w + (row - 32) * CCH + col)
                                      : (d_w + (row - 64) * CCH + col);
        float4 v = *reinterpret_cast<const float4*>(src);
        _Float16* dst = Wh + (size_t)row * CCH + col;
        dst[0] = (_Float16)v.x; dst[1] = (_Float16)v.y;
        dst[2] = (_Float16)v.z; dst[3] = (_Float16)v.w;
    } else {
        m_enc[(bid - 80) * 256 + tid] = 0u;
    }
}

// ---------------------------------------------------------------------------
// Projection kernel (round-6/7 verified, unchanged). D[m=pos][n=ch].
// Grid: 4 batches x 128 position-tiles of 32. Block 256 = 4 waves.
// ---------------------------------------------------------------------------
__global__ __launch_bounds__(256) void proj_kernel(
    const float* __restrict__ a, const _Float16* __restrict__ Wh,
    const float* __restrict__ b_b, const float* __restrict__ c_b,
    const float* __restrict__ d_b,
    _Float16* __restrict__ bqT, _Float16* __restrict__ ckT,
    _Float16* __restrict__ dv)
{
    __shared__ _Float16 aT[32][CCH + 24];   // [pos][ch]; stride 560 B (16B-mult)

    const int n    = blockIdx.x >> 7;
    const int i0   = (blockIdx.x & 127) << 5;
    const int tid  = threadIdx.x;
    const int lane = tid & 63;
    const int wave = tid >> 6;
    const int l15  = lane & 15;
    const int quad = lane >> 4;

    {
        const float* ap = a + (size_t)(n*CCH + tid)*NHW + i0;
        #pragma unroll
        for (int j = 0; j < 8; ++j) {
            float4 v = *reinterpret_cast<const float4*>(ap + j*4);
            aT[j*4+0][tid] = (_Float16)v.x;
            aT[j*4+1][tid] = (_Float16)v.y;
            aT[j*4+2][tid] = (_Float16)v.z;
            aT[j*4+3][tid] = (_Float16)v.w;
        }
    }
    __syncthreads();

    const f32x4 zf = {0.f, 0.f, 0.f, 0.f};
    f32x4 acc[5][2];
    #pragma unroll
    for (int t = 0; t < 5; ++t) { acc[t][0] = zf; acc[t][1] = zf; }

    const int ch0w = wave * 80;

    #pragma unroll
    for (int ks = 0; ks < 8; ++ks) {
        const int k0 = ks * 32;
        hv8 af0 = *reinterpret_cast<const hv8*>(&aT[l15][k0 + quad*8]);
        hv8 af1 = *reinterpret_cast<const hv8*>(&aT[16 + l15][k0 + quad*8]);
        #pragma unroll
        for (int t = 0; t < 5; ++t) {
            const int ch0 = ch0w + t*16;
            hv8 bf = *reinterpret_cast<const hv8*>(
                Wh + (size_t)(ch0 + l15)*CCH + k0 + quad*8);
            acc[t][0] = __builtin_amdgcn_mfma_f32_16x16x32_f16(af0, bf, acc[t][0], 0, 0, 0);
            acc[t][1] = __builtin_amdgcn_mfma_f32_16x16x32_f16(af1, bf, acc[t][1], 0, 0, 0);
        }
    }

    const int pos_b = i0 + quad*4;
    #pragma unroll
    for (int t = 0; t < 5; ++t) {
        const int ch0 = ch0w + t*16;
        if (ch0 < 64) {
            const float* bias_arr = (ch0 < 32) ? b_b : c_b;
            _Float16*    outp     = (ch0 < 32) ? bqT : ckT;
            const int    ch       = (ch0 & 31) + l15;
            const float  bias     = bias_arr[ch];
            #pragma unroll
            for (int nf = 0; nf < 2; ++nf) {
                #pragma unroll
                for (int r = 0; r < 4; ++r) {
                    const int pos = pos_b + nf*16 + r;
                    outp[((size_t)n*NHW + pos)*CQK + ch] =
                        (_Float16)(acc[t][nf][r] + bias);
                }
            }
        } else {
            const int ch   = ch0 - 64 + l15;
            const float bias = d_b[ch];
            #pragma unroll
            for (int nf = 0; nf < 2; ++nf) {
                hv4 v = { (_Float16)(acc[t][nf][0] + bias),
                          (_Float16)(acc[t][nf][1] + bias),
                          (_Float16)(acc[t][nf][2] + bias),
                          (_Float16)(acc[t][nf][3] + bias) };
                *reinterpret_cast<hv4*>(
                    dv + ((size_t)n*CCH + ch)*NHW + pos_b + nf*16) = v;
            }
        }
    }
}

// ---------------------------------------------------------------------------
// Pass A: per-q-row max, transposed S^T = K Q^T (round-9 verified, unchanged).
// Grid: 4n x 64qt x 4 k-splits = 1024.
// ---------------------------------------------------------------------------
__global__ __launch_bounds__(256) void rowmax_kernel(
    const _Float16* __restrict__ bqT, const _Float16* __restrict__ ckT,
    unsigned* __restrict__ m_enc)
{
    const int bx   = blockIdx.x;
    const int n    = bx >> 8;
    const int qt   = (bx >> 2) & 63;
    const int ks   = bx & 3;
    const int q0   = qt << 6;
    const int tid  = threadIdx.x;
    const int wave = tid >> 6;
    const int lane = tid & 63;
    const int l15  = lane & 15;
    const int quad = lane >> 4;

    const f32x4 zf = {0.f, 0.f, 0.f, 0.f};
    const hv8 qf = *reinterpret_cast<const hv8*>(
        bqT + ((size_t)n*NHW + q0 + wave*16 + l15)*CQK + quad*8);

    float mx = -1e30f;

    for (int kt = ks*16; kt < ks*16 + 16; ++kt) {
        const int k0 = kt << 6;
        #pragma unroll
        for (int f = 0; f < 4; ++f) {
            hv8 kf = *reinterpret_cast<const hv8*>(
                ckT + ((size_t)n*NHW + k0 + f*16 + l15)*CQK + quad*8);
            f32x4 s = __builtin_amdgcn_mfma_f32_16x16x32_f16(kf, qf, zf, 0, 0, 0);
            mx = fmaxf(mx, fmaxf(fmaxf(s[0], s[1]), fmaxf(s[2], s[3])));
        }
    }
    // reduce across quads (same l15 = same q)
    mx = fmaxf(mx, __shfl_xor(mx, 16, 64));
    mx = fmaxf(mx, __shfl_xor(mx, 32, 64));
    if (lane < 16)
        atomicMax(&m_enc[n*NHW + q0 + wave*16 + l15], enc_f32(mx));
}

// ---------------------------------------------------------------------------
// Pass B: flash attention, fixed row max, co-split 4 (grid 1024 = 4 blocks/CU).
// SOFTWARE-PIPELINED: p_lds is double-buffered per wave; iteration kt runs
// PV(kt) from p_lds[cur] (computed last iter) while computing S^T/exp(kt+1)
// into p_lds[cur^1] — PV's MFMA burst and exp's VALU burst are independent,
// so the pipes co-issue instead of serializing. kf for kt+1 is register-
// prefetched before PV so its latency is covered by the MFMA block.
// V tile double-buffered with one barrier per iter (round-7 verified).
// ---------------------------------------------------------------------------
__global__ __launch_bounds__(256) void attn_kernel(
    const _Float16* __restrict__ bqT, const _Float16* __restrict__ ckT,
    const _Float16* __restrict__ dv, const unsigned* __restrict__ m_enc,
    const float* __restrict__ a, const float* __restrict__ alpha_p,
    float* __restrict__ out)
{
    __shared__ _Float16 dv_lds[2][64 * 72];     // V tiles, 18.4 KB
    __shared__ _Float16 p_lds[2][4][16 * 72];   // per-wave P, dbuf, 18.4 KB

    const int bx   = blockIdx.x;
    const int n    = bx >> 8;
    const int cg   = (bx >> 6) & 3;
    const int q0   = (bx & 63) << 6;
    const int co0  = cg << 6;
    const int tid  = threadIdx.x;
    const int wave = tid >> 6;
    const int lane = tid & 63;
    const int l15  = lane & 15;
    const int quad = lane >> 4;

    const f32x4 zf = {0.f, 0.f, 0.f, 0.f};
    const float L2E = 1.4426950408889634f;
    const _Float16 one_h = (_Float16)1.0f;
    const hv8 ones = { one_h, one_h, one_h, one_h, one_h, one_h, one_h, one_h };

    const hv8 qf = *reinterpret_cast<const hv8*>(
        bqT + ((size_t)n*NHW + q0 + wave*16 + l15)*CQK + quad*8);

    // fixed max for this lane's q (=l15), prescaled for exp2
    const float mneg = -L2E * dec_f32(m_enc[n*NHW + q0 + wave*16 + l15]);

    f32x4 acc[4];
    #pragma unroll
    for (int t = 0; t < 4; ++t) acc[t] = zf;
    f32x4 acc_l = zf;                       // softmax denominator per q-row

    // staging map: thread -> (co row pair, 16 B segment)
    const int co_s = tid >> 3;          // 0..31
    const int c8_s = (tid & 7) << 3;    // 0..56
    const _Float16* dvs0 = dv + ((size_t)(n*CCH + co0 + co_s))*NHW + c8_s;
    const _Float16* dvs1 = dvs0 + (size_t)32 * NHW;

    // kf base pointer for this lane (advances by 16 rows per f-frag)
    const _Float16* ckbase = ckT + ((size_t)n*NHW + l15)*CQK + quad*8;

    // S^T/exp for a key tile -> p_lds[buf]  (per-wave region, no barrier)
    auto softmax_tile = [&](int buf, const hv8* kf) {
        #pragma unroll
        for (int f = 0; f < 4; ++f) {
            f32x4 s = __builtin_amdgcn_mfma_f32_16x16x32_f16(kf[f], qf, zf, 0, 0, 0);
            float p0 = __builtin_amdgcn_exp2f(fmaf(s[0], L2E, mneg));
            float p1 = __builtin_amdgcn_exp2f(fmaf(s[1], L2E, mneg));
            float p2 = __builtin_amdgcn_exp2f(fmaf(s[2], L2E, mneg));
            float p3 = __builtin_amdgcn_exp2f(fmaf(s[3], L2E, mneg));
            fv2 lo = __builtin_amdgcn_cvt_pkrtz(p0, p1);
            fv2 hi = __builtin_amdgcn_cvt_pkrtz(p2, p3);
            uint2 w;
            w.x = __builtin_bit_cast(unsigned, lo);
            w.y = __builtin_bit_cast(unsigned, hi);
            *reinterpret_cast<uint2*>(
                &p_lds[buf][wave][l15*72 + f*16 + quad*4]) = w;
        }
    };

    // ---- prologue: stage V tile 0, compute exp tile 0
    {
        int4 r0 = *reinterpret_cast<const int4*>(dvs0);
        int4 r1 = *reinterpret_cast<const int4*>(dvs1);
        *reinterpret_cast<int4*>(&dv_lds[0][co_s*72 + c8_s])        = r0;
        *reinterpret_cast<int4*>(&dv_lds[0][(co_s + 32)*72 + c8_s]) = r1;
        hv8 kf0[4];
        #pragma unroll
        for (int f = 0; f < 4; ++f)
            kf0[f] = *reinterpret_cast<const hv8*>(ckbase + (size_t)(f*16)*CQK);
        softmax_tile(0, kf0);
    }
    __syncthreads();

    for (int kt = 0; kt < 64; ++kt) {
        const int k0n = (kt + 1) << 6;      // next tile base
        const int cur = kt & 1;

        // ---- prefetch next tile: kf fragments + V rows (registers)
        hv8 kfn[4];
        int4 nr0, nr1;
        if (kt < 63) {
            #pragma unroll
            for (int f = 0; f < 4; ++f)
                kfn[f] = *reinterpret_cast<const hv8*>(
                    ckbase + (size_t)(k0n + f*16)*CQK);
            nr0 = *reinterpret_cast<const int4*>(dvs0 + k0n);
            nr1 = *reinterpret_cast<const int4*>(dvs1 + k0n);
        }

        // ---- PV(kt): fragments from p_lds[cur] (written last iter, same wave)
        hv8 pf0 = *reinterpret_cast<const hv8*>(&p_lds[cur][wave][l15*72 + quad*8]);
        hv8 pf1 = *reinterpret_cast<const hv8*>(&p_lds[cur][wave][l15*72 + 32 + quad*8]);
        #pragma unroll
        for (int t = 0; t < 4; ++t) {
            hv8 d0 = *reinterpret_cast<const hv8*>(&dv_lds[cur][(t*16 + l15)*72 + quad*8]);
            acc[t] = __builtin_amdgcn_mfma_f32_16x16x32_f16(pf0, d0, acc[t], 0, 0, 0);
            hv8 d1 = *reinterpret_cast<const hv8*>(&dv_lds[cur][(t*16 + l15)*72 + 32 + quad*8]);
            acc[t] = __builtin_amdgcn_mfma_f32_16x16x32_f16(pf1, d1, acc[t], 0, 0, 0);
        }
        acc_l = __builtin_amdgcn_mfma_f32_16x16x32_f16(pf0, ones, acc_l, 0, 0, 0);
        acc_l = __builtin_amdgcn_mfma_f32_16x16x32_f16(pf1, ones, acc_l, 0, 0, 0);

        // ---- S^T/exp(kt+1) into the other p buffer (overlaps PV above)
        if (kt < 63) {
            softmax_tile(cur ^ 1, kfn);
            // ---- stage next V tile, single barrier
            *reinterpret_cast<int4*>(&dv_lds[cur ^ 1][co_s*72 + c8_s])        = nr0;
            *reinterpret_cast<int4*>(&dv_lds[cur ^ 1][(co_s + 32)*72 + c8_s]) = nr1;
            __syncthreads();
        }
    }

    // ---- epilogue: out[co][q..q+3] = alpha*O/l + a, direct float4 per lane
    const float alpha = alpha_p[0];
    f32x4 rl;
    #pragma unroll
    for (int r = 0; r < 4; ++r) rl[r] = alpha / acc_l[r];

    const int qv = q0 + wave*16 + quad*4;
    #pragma unroll
    for (int t = 0; t < 4; ++t) {
        const int co = co0 + t*16 + l15;
        const size_t off = ((size_t)n*CCH + co)*NHW + qv;
        float4 av = *reinterpret_cast<const float4*>(a + off);
        float4 o;
        o.x = acc[t][0]*rl[0] + av.x;
        o.y = acc[t][1]*rl[1] + av.y;
        o.z = acc[t][2]*rl[2] + av.z;
        o.w = acc[t][3]*rl[3] + av.w;
        *reinterpret_cast<float4*>(out + off) = o;
    }
}

extern "C" void kernel_launch(void* const* d_in, const int* in_sizes, int n_in,
                              void* d_out, int out_size, void* d_ws, size_t ws_size,
                              hipStream_t stream)
{
    const float* a    = (const float*)d_in[0];
    const float* b_w  = (const float*)d_in[1];
    const float* b_b  = (const float*)d_in[2];
    const float* c_w  = (const float*)d_in[3];
    const float* c_b  = (const float*)d_in[4];
    const float* d_w  = (const float*)d_in[5];
    const float* d_b  = (const float*)d_in[6];
    const float* alp  = (const float*)d_in[7];
    float* out = (float*)d_out;

    _Float16* bqT  = (_Float16*)d_ws;                 // [4][4096][32] fp16, 1 MB
    _Float16* ckT  = bqT + (size_t)4*NHW*CQK;         // [4][4096][32] fp16, 1 MB
    _Float16* dv   = ckT + (size_t)4*NHW*CQK;         // [4][256][4096] fp16, 8 MB
    unsigned* m_enc = (unsigned*)(dv + (size_t)4*CCH*NHW);  // [4][4096] u32, 64 KB
    _Float16* Wh   = (_Float16*)(m_enc + 4*NHW);      // [320][256] fp16, 160 KB

    prep_kernel<<<144, 256, 0, stream>>>(b_w, c_w, d_w, Wh, m_enc);
    proj_kernel<<<512, 256, 0, stream>>>(a, Wh, b_b, c_b, d_b, bqT, ckT, dv);
    rowmax_kernel<<<1024, 256, 0, stream>>>(bqT, ckT, m_enc);
    attn_kernel<<<1024, 256, 0, stream>>>(bqT, ckT, dv, m_enc, a, alp, out);
}